// Round 10
// baseline (357.784 us; speedup 1.0000x reference)
//
#include <hip/hip_runtime.h>

#define NN 50000
#define EE 800000
#define NB 30
#define NK2 1152   // 9 * 128 (8 relations + loop) contracted dim for fused gemm
#define NSB 49
#define NPART 16
#define RANGE 3136
#define NSLICE 64
#define ESL 12500
#define NPAD 50176

typedef __attribute__((ext_vector_type(8))) short short8;
typedef __attribute__((ext_vector_type(4))) float f32x4;

__device__ __forceinline__ unsigned short f2bf(float f) {
  unsigned u = __float_as_uint(f);
  u += 0x7FFF + ((u >> 16) & 1);
  return (unsigned short)(u >> 16);
}
__device__ __forceinline__ float bf2f(unsigned short s) {
  return __uint_as_float(((unsigned)s) << 16);
}

// ---- fused prep: Wt2[o][r*128+i] (blocks 0..575), W2t, X->bf16 (blocks 576..6825) ----
__global__ __launch_bounds__(256) void k_prep(const float* __restrict__ wcomp,
                                              const float* __restrict__ bases,
                                              const float* __restrict__ loopw,
                                              const float* __restrict__ W2,
                                              const float* __restrict__ X,
                                              unsigned short* __restrict__ Wt2,
                                              unsigned short* __restrict__ W2t,
                                              unsigned short* __restrict__ Xbf) {
  int b = blockIdx.x;
  if (b < 576) {
    int idx = b * 256 + threadIdx.x;      // idx = (r*128+i)*128 + o
    int o = idx & 127;
    int ri = idx >> 7;                    // r*128+i
    int r = ri >> 7, i = ri & 127;
    float v;
    if (r < 8) {
      float s = 0.f;
#pragma unroll
      for (int bb = 0; bb < NB; ++bb)
        s = fmaf(wcomp[r * NB + bb], bases[((size_t)bb * 128 + i) * 128 + o], s);
      v = s;
    } else {
      v = loopw[i * 128 + o];
    }
    Wt2[(size_t)o * NK2 + ri] = f2bf(v);
    if (idx < 128 * 128) {
      int j = idx >> 7, k = idx & 127;
      W2t[idx] = f2bf(W2[k * 128 + j]);
    }
  } else {
    int i = ((b - 576) * 256 + threadIdx.x) * 4;
    float4 v = *(const float4*)(X + i);
    uint2 o;
    o.x = (unsigned)f2bf(v.x) | ((unsigned)f2bf(v.y) << 16);
    o.y = (unsigned)f2bf(v.z) | ((unsigned)f2bf(v.w) << 16);
    *(uint2*)(Xbf + i) = o;
  }
}

// ---- partitioned LDS degree histograms ----
__global__ __launch_bounds__(256) void k_hist(const int* __restrict__ EI,
                                              int* __restrict__ pdin, int* __restrict__ pdout) {
  __shared__ int hist[RANGE];
  int b = blockIdx.x;
  int kind = b & 1;
  int sl = (b >> 1) & (NSLICE - 1);
  int r = b >> 7;
  const int base = r * RANGE;
  const int* vals = kind ? EI : EI + EE;
  int* part = kind ? pdout : pdin;
  for (int j = threadIdx.x; j < RANGE; j += 256) hist[j] = 0;
  __syncthreads();
  const int e0 = sl * ESL;
  for (int i = threadIdx.x; i < ESL / 4; i += 256) {
    int4 d = *(const int4*)(vals + e0 + i * 4);
    int x;
    x = d.x - base; if ((unsigned)x < RANGE) atomicAdd(&hist[x], 1);
    x = d.y - base; if ((unsigned)x < RANGE) atomicAdd(&hist[x], 1);
    x = d.z - base; if ((unsigned)x < RANGE) atomicAdd(&hist[x], 1);
    x = d.w - base; if ((unsigned)x < RANGE) atomicAdd(&hist[x], 1);
  }
  __syncthreads();
  for (int j = threadIdx.x; j < RANGE; j += 256)
    part[sl * NPAD + base + j] = hist[j];
}

// ---- A) reduce partials + per-block sums ----
__global__ __launch_bounds__(256) void k_scan_a(const int* __restrict__ pdin,
                                                const int* __restrict__ pdout,
                                                int* __restrict__ din,
                                                int* __restrict__ dout,
                                                int* __restrict__ bsum) {
  __shared__ int wsum[4];
  int b = blockIdx.x, t = threadIdx.x;
  int lane = t & 63, w = t >> 6;
  int i0 = b * 1024 + t * 4;
  int4 acc = {0, 0, 0, 0}, od = {0, 0, 0, 0};
  for (int sl = 0; sl < NSLICE; ++sl) {
    int4 a = *(const int4*)(pdin + sl * NPAD + i0);
    int4 o = *(const int4*)(pdout + sl * NPAD + i0);
    acc.x += a.x; acc.y += a.y; acc.z += a.z; acc.w += a.w;
    od.x += o.x; od.y += o.y; od.z += o.z; od.w += o.w;
  }
  *(int4*)(din + i0) = acc;
  *(int4*)(dout + i0) = od;
  int sv = acc.x + acc.y + acc.z + acc.w;
#pragma unroll
  for (int off = 32; off; off >>= 1) sv += __shfl_down(sv, off, 64);
  if (lane == 0) wsum[w] = sv;
  __syncthreads();
  if (t == 0) bsum[b] = wsum[0] + wsum[1] + wsum[2] + wsum[3];
}

// ---- B) exclusive scan of block sums ----
__global__ void k_scan_b(int* __restrict__ bsum, int* __restrict__ row_ptr) {
  int t = threadIdx.x;
  int v = (t < NSB) ? bsum[t] : 0;
  int orig = v;
#pragma unroll
  for (int off = 1; off < 64; off <<= 1) {
    int u = __shfl_up(v, off, 64);
    if (t >= off) v += u;
  }
  if (t < NSB) bsum[t] = v - orig;
  if (t == 0) row_ptr[NN] = EE;
}

// ---- C) block-level exclusive scan -> row_ptr ----
__global__ __launch_bounds__(256) void k_scan_c(const int* __restrict__ din,
                                                const int* __restrict__ bsum,
                                                int* __restrict__ row_ptr) {
  __shared__ int wsum[4];
  int b = blockIdx.x, t = threadIdx.x;
  int lane = t & 63, w = t >> 6;
  int i0 = b * 1024 + t * 4;
  int4 d = *(const int4*)(din + i0);
  int sth = d.x + d.y + d.z + d.w;
  int v = sth;
#pragma unroll
  for (int off = 1; off < 64; off <<= 1) {
    int u = __shfl_up(v, off, 64);
    if (lane >= off) v += u;
  }
  if (lane == 63) wsum[w] = v;
  __syncthreads();
  int woff = 0;
  for (int j = 0; j < w; ++j) woff += wsum[j];
  int base = bsum[b] + woff + (v - sth);
  if (i0 + 0 <= NN) row_ptr[i0 + 0] = base; base += d.x;
  if (i0 + 1 <= NN) row_ptr[i0 + 1] = base; base += d.y;
  if (i0 + 2 <= NN) row_ptr[i0 + 2] = base; base += d.z;
  if (i0 + 3 <= NN) row_ptr[i0 + 3] = base;
}

// ---- D) pdin[sl][n] -> slice-start offsets ----
__global__ __launch_bounds__(256) void k_pfx(int* __restrict__ pdin,
                                             const int* __restrict__ row_ptr) {
  int n = blockIdx.x * 256 + threadIdx.x;
  int run = row_ptr[n];
#pragma unroll 8
  for (int sl = 0; sl < NSLICE; ++sl) {
    int c = pdin[sl * NPAD + n];
    pdin[sl * NPAD + n] = run;
    run += c;
  }
}

// ---- scatter: em = {(src<<4)|ety, enorm}, LDS cursors, no global atomics ----
__global__ __launch_bounds__(256) void k_scatter(const int* __restrict__ src,
                                                 const int* __restrict__ dst,
                                                 const int* __restrict__ ety,
                                                 const float* __restrict__ enorm,
                                                 const int* __restrict__ pdin,
                                                 int2* __restrict__ em) {
  __shared__ int cur[RANGE];
  int b = blockIdx.x;
  int sl = b & (NSLICE - 1), r = b >> 6;
  const int base = r * RANGE;
  for (int j = threadIdx.x; j < RANGE; j += 256)
    cur[j] = pdin[sl * NPAD + base + j];
  __syncthreads();
  const int e0 = sl * ESL;
  for (int i = threadIdx.x; i < ESL / 4; i += 256) {
    int4 d = *(const int4*)(dst + e0 + i * 4);
    int vals[4] = {d.x, d.y, d.z, d.w};
#pragma unroll
    for (int j = 0; j < 4; ++j) {
      int dv = vals[j] - base;
      if ((unsigned)dv < RANGE) {
        int e = e0 + i * 4 + j;
        int pos = atomicAdd(&cur[dv], 1);
        em[pos] = make_int2((src[e] << 4) | ety[e], __float_as_int(enorm[e]));
      }
    }
  }
}

#define UNR 8

// ---- layer-1 gather-reduce: Y[n][r*128+c] = sum_{e in CSR[n], ety=r} norm * Xbf[src] ----
// ty is WAVE-UNIFORM (all 64 lanes hold the same edge) -> scalar switch, 2 FMA/edge
__global__ __launch_bounds__(256) void k_agg0(const unsigned short* __restrict__ Xbf,
                                              const int2* __restrict__ em,
                                              const int* __restrict__ row_ptr,
                                              unsigned short* __restrict__ Y) {
  int gw = (blockIdx.x * blockDim.x + threadIdx.x) >> 6;
  int lane = threadIdx.x & 63;
  if (gw >= NN) return;
  int beg = row_ptr[gw], end = row_ptr[gw + 1];
  float a0[8], a1[8];
#pragma unroll
  for (int r = 0; r < 8; ++r) { a0[r] = 0.f; a1[r] = 0.f; }
  for (int i = beg; i < end; i += UNR) {
    int2 md[UNR];
    unsigned v[UNR];
#pragma unroll
    for (int j = 0; j < UNR; ++j) {
      int idx = i + j;
      idx = idx < end ? idx : end - 1;
      md[j] = em[idx];
      if (i + j >= end) md[j].y = 0;
    }
#pragma unroll
    for (int j = 0; j < UNR; ++j)
      v[j] = *(const unsigned*)(Xbf + ((size_t)((unsigned)md[j].x >> 4) << 7) + lane * 2);
#pragma unroll
    for (int j = 0; j < UNR; ++j) {
      float w = __int_as_float(md[j].y);
      float x0 = bf2f((unsigned short)(v[j] & 0xffff));
      float x1 = bf2f((unsigned short)(v[j] >> 16));
      int ty = __builtin_amdgcn_readfirstlane(md[j].x & 15);   // wave-uniform
      switch (ty) {
        case 0: a0[0] = fmaf(w, x0, a0[0]); a1[0] = fmaf(w, x1, a1[0]); break;
        case 1: a0[1] = fmaf(w, x0, a0[1]); a1[1] = fmaf(w, x1, a1[1]); break;
        case 2: a0[2] = fmaf(w, x0, a0[2]); a1[2] = fmaf(w, x1, a1[2]); break;
        case 3: a0[3] = fmaf(w, x0, a0[3]); a1[3] = fmaf(w, x1, a1[3]); break;
        case 4: a0[4] = fmaf(w, x0, a0[4]); a1[4] = fmaf(w, x1, a1[4]); break;
        case 5: a0[5] = fmaf(w, x0, a0[5]); a1[5] = fmaf(w, x1, a1[5]); break;
        case 6: a0[6] = fmaf(w, x0, a0[6]); a1[6] = fmaf(w, x1, a1[6]); break;
        default: a0[7] = fmaf(w, x0, a0[7]); a1[7] = fmaf(w, x1, a1[7]); break;
      }
    }
  }
  unsigned short* yr = Y + (size_t)gw * 1024 + lane * 2;
#pragma unroll
  for (int r = 0; r < 8; ++r) {
    unsigned o = (unsigned)f2bf(a0[r]) | ((unsigned)f2bf(a1[r]) << 16);
    *(unsigned*)(yr + r * 128) = o;
  }
}

// ---- fused gemm: hs = ((Y || Xbf) @ Wt2 + bias1) * outdeg^-1/2, bf16 out ----
__global__ __launch_bounds__(256) void k_gemmh(const unsigned short* __restrict__ Y,
                                               const unsigned short* __restrict__ Xbf,
                                               const unsigned short* __restrict__ Wt2,
                                               const int* __restrict__ dout,
                                               const float* __restrict__ bias1,
                                               unsigned short* __restrict__ hs) {
  __shared__ unsigned short As[64 * 136];
  __shared__ unsigned short Bs[128 * 136];
  const int m0 = blockIdx.x * 64;
  const int t = threadIdx.x;
  const int lane = t & 63, wave = t >> 6;
  const int wr = (wave >> 1) * 32, wc = (wave & 1) * 64;
  const int lr = lane & 15, lk = (lane >> 4) * 8;

  f32x4 acc[2][4];
#pragma unroll
  for (int m = 0; m < 2; ++m)
#pragma unroll
    for (int n = 0; n < 4; ++n) acc[m][n] = (f32x4){0.f, 0.f, 0.f, 0.f};

  for (int kt = 0; kt < 9; ++kt) {
    __syncthreads();
    for (int i = t; i < 1024; i += 256) {
      int r = i >> 4, c = i & 15;
      int n = m0 + r;
      uint4 va = {0, 0, 0, 0};
      if (n < NN) {
        const unsigned short* ap = (kt < 8) ? (Y + (size_t)n * 1024 + kt * 128)
                                            : (Xbf + (size_t)n * 128);
        va = *(const uint4*)(ap + c * 8);
      }
      *(uint4*)(&As[r * 136 + c * 8]) = va;
    }
    for (int i = t; i < 2048; i += 256) {
      int r = i >> 4, c = i & 15;
      uint4 vb = *(const uint4*)(Wt2 + (size_t)r * NK2 + kt * 128 + c * 8);
      *(uint4*)(&Bs[r * 136 + c * 8]) = vb;
    }
    __syncthreads();
#pragma unroll
    for (int s = 0; s < 4; ++s) {
      short8 af[2], bfv[4];
#pragma unroll
      for (int m = 0; m < 2; ++m)
        af[m] = *(const short8*)(&As[(wr + m * 16 + lr) * 136 + s * 32 + lk]);
#pragma unroll
      for (int n = 0; n < 4; ++n)
        bfv[n] = *(const short8*)(&Bs[(wc + n * 16 + lr) * 136 + s * 32 + lk]);
#pragma unroll
      for (int m = 0; m < 2; ++m)
#pragma unroll
        for (int n = 0; n < 4; ++n)
          acc[m][n] = __builtin_amdgcn_mfma_f32_16x16x32_bf16(af[m], bfv[n], acc[m][n], 0, 0, 0);
    }
  }

#pragma unroll
  for (int m = 0; m < 2; ++m) {
#pragma unroll
    for (int i = 0; i < 4; ++i) {
      int row = m0 + wr + m * 16 + (lane >> 4) * 4 + i;
      if (row >= NN) continue;
      float ns = rsqrtf(fmaxf((float)dout[row], 1.f));
      unsigned short* hr = hs + (size_t)row * 128 + wc;
#pragma unroll
      for (int n = 0; n < 4; ++n)
        hr[n * 16 + lr] = f2bf((acc[m][n][i] + bias1[wc + n * 16 + lr]) * ns);
    }
  }
}

// ---- layer-2 aggregation: src = em.x >> 4 ----
__global__ __launch_bounds__(256) void k_agg2(const unsigned short* __restrict__ hs,
                                              const int2* __restrict__ em,
                                              const int* __restrict__ row_ptr,
                                              unsigned short* __restrict__ zb) {
  int gw = (blockIdx.x * blockDim.x + threadIdx.x) >> 6;
  int lane = threadIdx.x & 63;
  if (gw >= NN) return;
  int beg = row_ptr[gw], end = row_ptr[gw + 1];
  float a0 = 0.f, a1 = 0.f;
  for (int i = beg; i < end; i += UNR) {
    int2 md[UNR];
    unsigned v[UNR];
#pragma unroll
    for (int j = 0; j < UNR; ++j) {
      int idx = i + j;
      idx = idx < end ? idx : end - 1;
      md[j] = em[idx];
      if (i + j >= end) md[j].y = 0;
    }
#pragma unroll
    for (int j = 0; j < UNR; ++j)
      v[j] = *(const unsigned*)(hs + ((size_t)((unsigned)md[j].x >> 4) << 7) + lane * 2);
#pragma unroll
    for (int j = 0; j < UNR; ++j) {
      float w = __int_as_float(md[j].y);
      a0 = fmaf(w, bf2f((unsigned short)(v[j] & 0xffff)), a0);
      a1 = fmaf(w, bf2f((unsigned short)(v[j] >> 16)), a1);
    }
  }
  float nd = rsqrtf(fmaxf((float)(end - beg), 1.f));
  unsigned o = (unsigned)f2bf(a0 * nd) | ((unsigned)f2bf(a1 * nd) << 16);
  *(unsigned*)(zb + (size_t)gw * 128 + lane * 2) = o;
}

// ---- final GEMM: out = zb @ W2t^T + bias2 (f32 out) ----
__global__ __launch_bounds__(256) void k_gemm(const unsigned short* __restrict__ A,
                                              const unsigned short* __restrict__ B,
                                              float* __restrict__ Cf,
                                              const float* __restrict__ bias,
                                              int M, int ldc) {
  __shared__ unsigned short As[128 * 136];
  __shared__ unsigned short Bs[128 * 136];
  const int m0 = blockIdx.x * 128, j0 = 0;
  const int t = threadIdx.x;
  for (int i = t; i < 2048; i += 256) {
    int r = i >> 4, c = i & 15;
    uint4 va = {0, 0, 0, 0};
    int gr = m0 + r;
    if (gr < M) va = *(const uint4*)(A + (size_t)gr * 128 + c * 8);
    *(uint4*)(&As[r * 136 + c * 8]) = va;
    uint4 vb = *(const uint4*)(B + (size_t)(j0 + r) * 128 + c * 8);
    *(uint4*)(&Bs[r * 136 + c * 8]) = vb;
  }
  __syncthreads();

  const int lane = t & 63, wave = t >> 6;
  const int wr = (wave >> 1) * 64, wc = (wave & 1) * 64;
  const int lr = lane & 15, lk = (lane >> 4) * 8;

  f32x4 acc[4][4];
#pragma unroll
  for (int m = 0; m < 4; ++m)
#pragma unroll
    for (int n = 0; n < 4; ++n) acc[m][n] = (f32x4){0.f, 0.f, 0.f, 0.f};

#pragma unroll
  for (int kt = 0; kt < 4; ++kt) {
    short8 af[4], bfr[4];
#pragma unroll
    for (int m = 0; m < 4; ++m)
      af[m] = *(const short8*)(&As[(wr + m * 16 + lr) * 136 + kt * 32 + lk]);
#pragma unroll
    for (int n = 0; n < 4; ++n)
      bfr[n] = *(const short8*)(&Bs[(wc + n * 16 + lr) * 136 + kt * 32 + lk]);
#pragma unroll
    for (int m = 0; m < 4; ++m)
#pragma unroll
      for (int n = 0; n < 4; ++n)
        acc[m][n] = __builtin_amdgcn_mfma_f32_16x16x32_bf16(af[m], bfr[n], acc[m][n], 0, 0, 0);
  }

#pragma unroll
  for (int m = 0; m < 4; ++m) {
    int rbase = m0 + wr + m * 16 + (lane >> 4) * 4;
#pragma unroll
    for (int i = 0; i < 4; ++i) {
      int row = rbase + i;
      if (row >= M) continue;
      float* cr = Cf + (size_t)row * ldc + j0 + wc;
#pragma unroll
      for (int n = 0; n < 4; ++n) cr[n * 16 + lr] = acc[m][n][i] + bias[j0 + wc + n * 16 + lr];
    }
  }
}

extern "C" void kernel_launch(void* const* d_in, const int* in_sizes, int n_in,
                              void* d_out, int out_size, void* d_ws, size_t ws_size,
                              hipStream_t stream) {
  const float* X = (const float*)d_in[0];
  const int* EI = (const int*)d_in[1];
  const float* enorm = (const float*)d_in[2];
  const int* etype = (const int*)d_in[3];
  const float* wcomp = (const float*)d_in[4];
  const float* bases = (const float*)d_in[5];
  const float* loopw = (const float*)d_in[6];
  const float* bias1 = (const float*)d_in[7];
  const float* W2 = (const float*)d_in[8];
  const float* bias2 = (const float*)d_in[9];
  float* out = (float*)d_out;
  const int* srcA = EI;
  const int* dstA = EI + EE;

  char* p = (char*)d_ws;
  auto alloc = [&](size_t bytes) {
    char* r = p;
    p += (bytes + 255) & ~(size_t)255;
    return r;
  };
  unsigned short* Y   = (unsigned short*)alloc((size_t)NN * 1024 * 2);  // 102.4 MB
  unsigned short* Xbf = (unsigned short*)alloc((size_t)NN * 128 * 2);
  unsigned short* hs  = (unsigned short*)alloc((size_t)NN * 128 * 2);
  unsigned short* zb  = (unsigned short*)alloc((size_t)NN * 128 * 2);
  unsigned short* Wt2 = (unsigned short*)alloc((size_t)128 * NK2 * 2);
  unsigned short* W2t = (unsigned short*)alloc(128 * 128 * 2);
  int* pdin    = (int*)alloc((size_t)NSLICE * NPAD * 4);
  int* pdout   = (int*)alloc((size_t)NSLICE * NPAD * 4);
  int* din     = (int*)alloc((size_t)NPAD * 4);
  int* dout    = (int*)alloc((size_t)NPAD * 4);
  int* row_ptr = (int*)alloc((size_t)(NPAD + 1) * 4);
  int* bsum    = (int*)alloc((size_t)NSB * 4);
  int2* em     = (int2*)alloc((size_t)EE * 8);

  hipLaunchKernelGGL(k_prep, dim3(6826), dim3(256), 0, stream,
                     wcomp, bases, loopw, W2, X, Wt2, W2t, Xbf);
  hipLaunchKernelGGL(k_hist, dim3(2048), dim3(256), 0, stream, EI, pdin, pdout);
  hipLaunchKernelGGL(k_scan_a, dim3(NSB), dim3(256), 0, stream, pdin, pdout, din, dout, bsum);
  hipLaunchKernelGGL(k_scan_b, dim3(1), dim3(64), 0, stream, bsum, row_ptr);
  hipLaunchKernelGGL(k_scan_c, dim3(NSB), dim3(256), 0, stream, din, bsum, row_ptr);
  hipLaunchKernelGGL(k_pfx, dim3(NPAD / 256), dim3(256), 0, stream, pdin, row_ptr);
  hipLaunchKernelGGL(k_scatter, dim3(1024), dim3(256), 0, stream,
                     srcA, dstA, etype, enorm, pdin, em);
  hipLaunchKernelGGL(k_agg0, dim3(12500), dim3(256), 0, stream, Xbf, em, row_ptr, Y);
  hipLaunchKernelGGL(k_gemmh, dim3(782), dim3(256), 0, stream,
                     Y, Xbf, Wt2, dout, bias1, hs);
  hipLaunchKernelGGL(k_agg2, dim3(12500), dim3(256), 0, stream, hs, em, row_ptr, zb);
  hipLaunchKernelGGL(k_gemm, dim3(391), dim3(256), 0, stream,
                     zb, W2t, out, bias2, NN, 128);
}

// Round 11
// 339.722 us; speedup vs baseline: 1.0532x; 1.0532x over previous
//
#include <hip/hip_runtime.h>

#define NN 50000
#define EE 800000
#define NB 30
#define NJ 1152   // 8 relations * 128 + 128 loop cols
#define NSB 49
#define NPART 16
#define RANGE 3136
#define NSLICE 64
#define ESL 12500
#define NPAD 50176

typedef __attribute__((ext_vector_type(8))) short short8;
typedef __attribute__((ext_vector_type(4))) float f32x4;

__device__ __forceinline__ unsigned short f2bf(float f) {
  unsigned u = __float_as_uint(f);
  u += 0x7FFF + ((u >> 16) & 1);
  return (unsigned short)(u >> 16);
}
__device__ __forceinline__ float bf2f(unsigned short s) {
  return __uint_as_float(((unsigned)s) << 16);
}

// ---- fused prep (Wt/W2t blocks 0..575, X->bf16 blocks 576..6825) + hist (6826..8873) ----
__global__ __launch_bounds__(256) void k_prep_hist(const float* __restrict__ wcomp,
                                                   const float* __restrict__ bases,
                                                   const float* __restrict__ loopw,
                                                   const float* __restrict__ W2,
                                                   const float* __restrict__ X,
                                                   const int* __restrict__ EI,
                                                   unsigned short* __restrict__ Wt,
                                                   unsigned short* __restrict__ W2t,
                                                   unsigned short* __restrict__ Xbf,
                                                   int* __restrict__ pdin,
                                                   int* __restrict__ pdout) {
  __shared__ int hist[RANGE];
  int b = blockIdx.x;
  if (b < 576) {
    int idx = b * 256 + threadIdx.x;   // idx = j*128 + k, j = col (r*128+o), k = K index
    int j = idx >> 7, k = idx & 127;
    float v;
    if (j < 1024) {
      int r = j >> 7, o = j & 127;
      float s = 0.f;
#pragma unroll
      for (int bb = 0; bb < NB; ++bb)
        s = fmaf(wcomp[r * NB + bb], bases[((size_t)bb * 128 + k) * 128 + o], s);
      v = s;
    } else {
      v = loopw[k * 128 + (j - 1024)];
    }
    Wt[idx] = f2bf(v);
    if (idx < 128 * 128) W2t[idx] = f2bf(W2[k * 128 + j]);
  } else if (b < 6826) {
    int i = ((b - 576) * 256 + threadIdx.x) * 4;
    float4 v = *(const float4*)(X + i);
    uint2 o;
    o.x = (unsigned)f2bf(v.x) | ((unsigned)f2bf(v.y) << 16);
    o.y = (unsigned)f2bf(v.z) | ((unsigned)f2bf(v.w) << 16);
    *(uint2*)(Xbf + i) = o;
  } else {
    int b2 = b - 6826;                 // 0..2047
    int kind = b2 & 1;
    int sl = (b2 >> 1) & (NSLICE - 1);
    int r = b2 >> 7;
    const int base = r * RANGE;
    const int* vals = kind ? EI : EI + EE;   // kind1: src, kind0: dst
    int* part = kind ? pdout : pdin;
    for (int j = threadIdx.x; j < RANGE; j += 256) hist[j] = 0;
    __syncthreads();
    const int e0 = sl * ESL;
    for (int i = threadIdx.x; i < ESL / 4; i += 256) {
      int4 d = *(const int4*)(vals + e0 + i * 4);
      int x;
      x = d.x - base; if ((unsigned)x < RANGE) atomicAdd(&hist[x], 1);
      x = d.y - base; if ((unsigned)x < RANGE) atomicAdd(&hist[x], 1);
      x = d.z - base; if ((unsigned)x < RANGE) atomicAdd(&hist[x], 1);
      x = d.w - base; if ((unsigned)x < RANGE) atomicAdd(&hist[x], 1);
    }
    __syncthreads();
    for (int j = threadIdx.x; j < RANGE; j += 256)
      part[sl * NPAD + base + j] = hist[j];
  }
}

// ---- A) reduce partials (din & dout) + per-block sums of din ----
__global__ __launch_bounds__(256) void k_scan_a(const int* __restrict__ pdin,
                                                const int* __restrict__ pdout,
                                                int* __restrict__ din,
                                                int* __restrict__ dout,
                                                int* __restrict__ bsum) {
  __shared__ int wsum[4];
  int b = blockIdx.x, t = threadIdx.x;
  int lane = t & 63, w = t >> 6;
  int i0 = b * 1024 + t * 4;
  int4 acc = {0, 0, 0, 0}, od = {0, 0, 0, 0};
  for (int sl = 0; sl < NSLICE; ++sl) {
    int4 a = *(const int4*)(pdin + sl * NPAD + i0);
    int4 o = *(const int4*)(pdout + sl * NPAD + i0);
    acc.x += a.x; acc.y += a.y; acc.z += a.z; acc.w += a.w;
    od.x += o.x; od.y += o.y; od.z += o.z; od.w += o.w;
  }
  *(int4*)(din + i0) = acc;
  *(int4*)(dout + i0) = od;
  int sv = acc.x + acc.y + acc.z + acc.w;
#pragma unroll
  for (int off = 32; off; off >>= 1) sv += __shfl_down(sv, off, 64);
  if (lane == 0) wsum[w] = sv;
  __syncthreads();
  if (t == 0) bsum[b] = wsum[0] + wsum[1] + wsum[2] + wsum[3];
}

// ---- C) block-level exclusive scan (bsum scanned inline) -> row_ptr ----
__global__ __launch_bounds__(256) void k_scan_c(const int* __restrict__ din,
                                                const int* __restrict__ bsum,
                                                int* __restrict__ row_ptr) {
  __shared__ int wsum[4];
  int b = blockIdx.x, t = threadIdx.x;
  int lane = t & 63, w = t >> 6;
  int i0 = b * 1024 + t * 4;
  int4 d = *(const int4*)(din + i0);
  int sth = d.x + d.y + d.z + d.w;
  int v = sth;
#pragma unroll
  for (int off = 1; off < 64; off <<= 1) {
    int u = __shfl_up(v, off, 64);
    if (lane >= off) v += u;
  }
  if (lane == 63) wsum[w] = v;
  __syncthreads();
  int woff = 0;
  for (int j = 0; j < w; ++j) woff += wsum[j];
  int boff = 0;
  for (int j = 0; j < b; ++j) boff += bsum[j];   // <=48 L2-cached scalar reads
  int base = boff + woff + (v - sth);
  if (i0 + 0 <= NN) row_ptr[i0 + 0] = base; base += d.x;
  if (i0 + 1 <= NN) row_ptr[i0 + 1] = base; base += d.y;
  if (i0 + 2 <= NN) row_ptr[i0 + 2] = base; base += d.z;
  if (i0 + 3 <= NN) row_ptr[i0 + 3] = base;
}

// ---- D) pdin[sl][n] -> slice-start offsets ----
__global__ __launch_bounds__(256) void k_pfx(int* __restrict__ pdin,
                                             const int* __restrict__ row_ptr) {
  int n = blockIdx.x * 256 + threadIdx.x;
  int run = row_ptr[n];
#pragma unroll 8
  for (int sl = 0; sl < NSLICE; ++sl) {
    int c = pdin[sl * NPAD + n];
    pdin[sl * NPAD + n] = run;
    run += c;
  }
}

// ---- scatter: em = {src*NJ + ety*128, enorm}, LDS cursors, no global atomics ----
__global__ __launch_bounds__(256) void k_scatter(const int* __restrict__ src,
                                                 const int* __restrict__ dst,
                                                 const int* __restrict__ ety,
                                                 const float* __restrict__ enorm,
                                                 const int* __restrict__ pdin,
                                                 int2* __restrict__ em) {
  __shared__ int cur[RANGE];
  int b = blockIdx.x;
  int sl = b & (NSLICE - 1), r = b >> 6;
  const int base = r * RANGE;
  for (int j = threadIdx.x; j < RANGE; j += 256)
    cur[j] = pdin[sl * NPAD + base + j];
  __syncthreads();
  const int e0 = sl * ESL;
  for (int i = threadIdx.x; i < ESL / 4; i += 256) {
    int4 d = *(const int4*)(dst + e0 + i * 4);
    int vals[4] = {d.x, d.y, d.z, d.w};
#pragma unroll
    for (int j = 0; j < 4; ++j) {
      int dv = vals[j] - base;
      if ((unsigned)dv < RANGE) {
        int e = e0 + i * 4 + j;
        int pos = atomicAdd(&cur[dv], 1);
        em[pos] = make_int2(src[e] * NJ + ety[e] * 128, __float_as_int(enorm[e]));
      }
    }
  }
}

// ---- gemm1: xw[M][NJ] = Xbf[M][128] * Wt^T; A in LDS (34KB), B direct from L2 ----
__global__ __launch_bounds__(256, 4) void k_gemm1(const unsigned short* __restrict__ A,
                                                  const unsigned short* __restrict__ B,
                                                  unsigned short* __restrict__ C) {
  __shared__ unsigned short As[128 * 136];
  const int m0 = blockIdx.x * 128, j0 = blockIdx.y * 128;
  const int t = threadIdx.x;
  for (int i = t; i < 2048; i += 256) {
    int r = i >> 4, c = i & 15;
    uint4 va = {0, 0, 0, 0};
    int gr = m0 + r;
    if (gr < NN) va = *(const uint4*)(A + (size_t)gr * 128 + c * 8);
    *(uint4*)(&As[r * 136 + c * 8]) = va;
  }
  __syncthreads();

  const int lane = t & 63, wave = t >> 6;
  const int wr = (wave >> 1) * 64, wc = (wave & 1) * 64;
  const int lr = lane & 15, lk = (lane >> 4) * 8;

  f32x4 acc[4][4];
#pragma unroll
  for (int m = 0; m < 4; ++m)
#pragma unroll
    for (int n = 0; n < 4; ++n) acc[m][n] = (f32x4){0.f, 0.f, 0.f, 0.f};

#pragma unroll
  for (int kt = 0; kt < 4; ++kt) {
    short8 af[4], bfv[4];
#pragma unroll
    for (int n = 0; n < 4; ++n)
      bfv[n] = *(const short8*)(B + (size_t)(j0 + wc + n * 16 + lr) * 128 + kt * 32 + lk);
#pragma unroll
    for (int m = 0; m < 4; ++m)
      af[m] = *(const short8*)(&As[(wr + m * 16 + lr) * 136 + kt * 32 + lk]);
#pragma unroll
    for (int m = 0; m < 4; ++m)
#pragma unroll
      for (int n = 0; n < 4; ++n)
        acc[m][n] = __builtin_amdgcn_mfma_f32_16x16x32_bf16(af[m], bfv[n], acc[m][n], 0, 0, 0);
  }

#pragma unroll
  for (int m = 0; m < 4; ++m) {
    int rbase = m0 + wr + m * 16 + (lane >> 4) * 4;
#pragma unroll
    for (int i = 0; i < 4; ++i) {
      int row = rbase + i;
      if (row >= NN) continue;
      unsigned short* cr = C + (size_t)row * NJ + j0 + wc;
#pragma unroll
      for (int n = 0; n < 4; ++n) cr[n * 16 + lr] = f2bf(acc[m][n][i]);
    }
  }
}

#define UNR 8

// ---- layer-1 aggregation: wave per dst node, 8-wide ILP unroll ----
__global__ __launch_bounds__(256) void k_agg1(const unsigned short* __restrict__ xw,
                                              const int2* __restrict__ em,
                                              const int* __restrict__ row_ptr,
                                              const int* __restrict__ deg_out,
                                              const float* __restrict__ bias1,
                                              unsigned short* __restrict__ hs) {
  int gw = (blockIdx.x * blockDim.x + threadIdx.x) >> 6;
  int lane = threadIdx.x & 63;
  if (gw >= NN) return;
  int beg = row_ptr[gw], end = row_ptr[gw + 1];
  float a0 = 0.f, a1 = 0.f;
  for (int i = beg; i < end; i += UNR) {
    int2 md[UNR];
    unsigned v[UNR];
#pragma unroll
    for (int j = 0; j < UNR; ++j) {
      int idx = i + j;
      idx = idx < end ? idx : end - 1;
      md[j] = em[idx];
      if (i + j >= end) md[j].y = 0;
    }
#pragma unroll
    for (int j = 0; j < UNR; ++j)
      v[j] = *(const unsigned*)(xw + (size_t)(unsigned)md[j].x + lane * 2);
#pragma unroll
    for (int j = 0; j < UNR; ++j) {
      float w = __int_as_float(md[j].y);
      a0 = fmaf(w, bf2f((unsigned short)(v[j] & 0xffff)), a0);
      a1 = fmaf(w, bf2f((unsigned short)(v[j] >> 16)), a1);
    }
  }
  unsigned vl = *(const unsigned*)(xw + (size_t)gw * NJ + 1024 + lane * 2);
  float ns = rsqrtf(fmaxf((float)deg_out[gw], 1.f));
  float h0 = (a0 + bf2f((unsigned short)(vl & 0xffff)) + bias1[lane * 2]) * ns;
  float h1 = (a1 + bf2f((unsigned short)(vl >> 16)) + bias1[lane * 2 + 1]) * ns;
  unsigned o = (unsigned)f2bf(h0) | ((unsigned)f2bf(h1) << 16);
  *(unsigned*)(hs + (size_t)gw * 128 + lane * 2) = o;
}

// ---- layer-2 aggregation: src = (em.x >> 7) / 9 ----
__global__ __launch_bounds__(256) void k_agg2(const unsigned short* __restrict__ hs,
                                              const int2* __restrict__ em,
                                              const int* __restrict__ row_ptr,
                                              unsigned short* __restrict__ zb) {
  int gw = (blockIdx.x * blockDim.x + threadIdx.x) >> 6;
  int lane = threadIdx.x & 63;
  if (gw >= NN) return;
  int beg = row_ptr[gw], end = row_ptr[gw + 1];
  float a0 = 0.f, a1 = 0.f;
  for (int i = beg; i < end; i += UNR) {
    int2 md[UNR];
    unsigned v[UNR];
#pragma unroll
    for (int j = 0; j < UNR; ++j) {
      int idx = i + j;
      idx = idx < end ? idx : end - 1;
      md[j] = em[idx];
      if (i + j >= end) md[j].y = 0;
    }
#pragma unroll
    for (int j = 0; j < UNR; ++j) {
      unsigned srcn = (((unsigned)md[j].x) >> 7) / 9u;
      v[j] = *(const unsigned*)(hs + ((size_t)srcn << 7) + lane * 2);
    }
#pragma unroll
    for (int j = 0; j < UNR; ++j) {
      float w = __int_as_float(md[j].y);
      a0 = fmaf(w, bf2f((unsigned short)(v[j] & 0xffff)), a0);
      a1 = fmaf(w, bf2f((unsigned short)(v[j] >> 16)), a1);
    }
  }
  float nd = rsqrtf(fmaxf((float)(end - beg), 1.f));
  unsigned o = (unsigned)f2bf(a0 * nd) | ((unsigned)f2bf(a1 * nd) << 16);
  *(unsigned*)(zb + (size_t)gw * 128 + lane * 2) = o;
}

// ---- final GEMM: out = zb @ W2t^T + bias2 (f32 out) ----
__global__ __launch_bounds__(256) void k_gemm2(const unsigned short* __restrict__ A,
                                               const unsigned short* __restrict__ B,
                                               float* __restrict__ Cf,
                                               const float* __restrict__ bias) {
  __shared__ unsigned short As[128 * 136];
  __shared__ unsigned short Bs[128 * 136];
  const int m0 = blockIdx.x * 128;
  const int t = threadIdx.x;
  for (int i = t; i < 2048; i += 256) {
    int r = i >> 4, c = i & 15;
    uint4 va = {0, 0, 0, 0};
    int gr = m0 + r;
    if (gr < NN) va = *(const uint4*)(A + (size_t)gr * 128 + c * 8);
    *(uint4*)(&As[r * 136 + c * 8]) = va;
    uint4 vb = *(const uint4*)(B + (size_t)r * 128 + c * 8);
    *(uint4*)(&Bs[r * 136 + c * 8]) = vb;
  }
  __syncthreads();

  const int lane = t & 63, wave = t >> 6;
  const int wr = (wave >> 1) * 64, wc = (wave & 1) * 64;
  const int lr = lane & 15, lk = (lane >> 4) * 8;

  f32x4 acc[4][4];
#pragma unroll
  for (int m = 0; m < 4; ++m)
#pragma unroll
    for (int n = 0; n < 4; ++n) acc[m][n] = (f32x4){0.f, 0.f, 0.f, 0.f};

#pragma unroll
  for (int kt = 0; kt < 4; ++kt) {
    short8 af[4], bfr[4];
#pragma unroll
    for (int m = 0; m < 4; ++m)
      af[m] = *(const short8*)(&As[(wr + m * 16 + lr) * 136 + kt * 32 + lk]);
#pragma unroll
    for (int n = 0; n < 4; ++n)
      bfr[n] = *(const short8*)(&Bs[(wc + n * 16 + lr) * 136 + kt * 32 + lk]);
#pragma unroll
    for (int m = 0; m < 4; ++m)
#pragma unroll
      for (int n = 0; n < 4; ++n)
        acc[m][n] = __builtin_amdgcn_mfma_f32_16x16x32_bf16(af[m], bfr[n], acc[m][n], 0, 0, 0);
  }

#pragma unroll
  for (int m = 0; m < 4; ++m) {
    int rbase = m0 + wr + m * 16 + (lane >> 4) * 4;
#pragma unroll
    for (int i = 0; i < 4; ++i) {
      int row = rbase + i;
      if (row >= NN) continue;
      float* cr = Cf + (size_t)row * 128 + wc;
#pragma unroll
      for (int n = 0; n < 4; ++n) cr[n * 16 + lr] = acc[m][n][i] + bias[wc + n * 16 + lr];
    }
  }
}

extern "C" void kernel_launch(void* const* d_in, const int* in_sizes, int n_in,
                              void* d_out, int out_size, void* d_ws, size_t ws_size,
                              hipStream_t stream) {
  const float* X = (const float*)d_in[0];
  const int* EI = (const int*)d_in[1];
  const float* enorm = (const float*)d_in[2];
  const int* etype = (const int*)d_in[3];
  const float* wcomp = (const float*)d_in[4];
  const float* bases = (const float*)d_in[5];
  const float* loopw = (const float*)d_in[6];
  const float* bias1 = (const float*)d_in[7];
  const float* W2 = (const float*)d_in[8];
  const float* bias2 = (const float*)d_in[9];
  float* out = (float*)d_out;
  const int* srcA = EI;
  const int* dstA = EI + EE;

  char* p = (char*)d_ws;
  auto alloc = [&](size_t bytes) {
    char* r = p;
    p += (bytes + 255) & ~(size_t)255;
    return r;
  };
  unsigned short* xw  = (unsigned short*)alloc((size_t)NN * NJ * 2);  // 115.2 MB
  unsigned short* Xbf = (unsigned short*)alloc((size_t)NN * 128 * 2);
  unsigned short* hs  = (unsigned short*)alloc((size_t)NN * 128 * 2);
  unsigned short* zb  = (unsigned short*)alloc((size_t)NN * 128 * 2);
  unsigned short* Wt  = (unsigned short*)alloc((size_t)NJ * 128 * 2);
  unsigned short* W2t = (unsigned short*)alloc(128 * 128 * 2);
  int* pdin    = (int*)alloc((size_t)NSLICE * NPAD * 4);
  int* pdout   = (int*)alloc((size_t)NSLICE * NPAD * 4);
  int* din     = (int*)alloc((size_t)NPAD * 4);
  int* dout    = (int*)alloc((size_t)NPAD * 4);
  int* row_ptr = (int*)alloc((size_t)(NPAD + 1) * 4);
  int* bsum    = (int*)alloc((size_t)NSB * 4);
  int2* em     = (int2*)alloc((size_t)EE * 8);

  hipLaunchKernelGGL(k_prep_hist, dim3(8874), dim3(256), 0, stream,
                     wcomp, bases, loopw, W2, X, EI, Wt, W2t, Xbf, pdin, pdout);
  hipLaunchKernelGGL(k_scan_a, dim3(NSB), dim3(256), 0, stream, pdin, pdout, din, dout, bsum);
  hipLaunchKernelGGL(k_scan_c, dim3(NSB), dim3(256), 0, stream, din, bsum, row_ptr);
  hipLaunchKernelGGL(k_pfx, dim3(NPAD / 256), dim3(256), 0, stream, pdin, row_ptr);
  hipLaunchKernelGGL(k_scatter, dim3(1024), dim3(256), 0, stream,
                     srcA, dstA, etype, enorm, pdin, em);
  hipLaunchKernelGGL(k_gemm1, dim3(391, 9), dim3(256), 0, stream, Xbf, Wt, xw);
  hipLaunchKernelGGL(k_agg1, dim3(12500), dim3(256), 0, stream,
                     xw, em, row_ptr, dout, bias1, hs);
  hipLaunchKernelGGL(k_agg2, dim3(12500), dim3(256), 0, stream, hs, em, row_ptr, zb);
  hipLaunchKernelGGL(k_gemm2, dim3(391), dim3(256), 0, stream, zb, W2t, out, bias2);
}